// Round 3
// baseline (172.096 us; speedup 1.0000x reference)
//
#include <hip/hip_runtime.h>

#define NA 8
#define NV 16
#define NS (NA * NV)          // 128 segments
#define NP 4                  // attribute pairs
#define NJ 256                // joint entries per pair (16*16)
#define FIX_SHIFT 43
#define FIX_MASK ((1ULL << FIX_SHIFT) - 1)
#define FIX_SCALE 2147483648.0f   // 2^31

// ---------------------------------------------------------------------------
// K1: per-row sigmoid mean -> FOUR packed ds_add_u64 (one per attr PAIR) into
// 256-entry joint histograms. Joint idx = v_even*16 + v_odd. 64 lanes scatter
// over 256 addresses -> ~1.2 lanes/address (vs 4 with per-attr histograms),
// killing same-address RMW serialization; atomic count halves.
// packed = count<<43 | round(per_node * 2^31). rows/block <= 977 @ nb=2048
// -> sum < 2^41, count < 2^10: no field overflow.
// Epilogue: 1024 plain stores, transposed [entry][block] for K2 coalescing.
// ---------------------------------------------------------------------------
__global__ __launch_bounds__(256) void k1_accum(
    const float* __restrict__ preds,           // [B, 8]
    const int*   __restrict__ attrs,           // [B, 8]
    unsigned long long* __restrict__ partials, // [NP*NJ, nb]
    int B, int nb)
{
    __shared__ unsigned long long h[NP * NJ];   // 8 KB
    for (int i = threadIdx.x; i < NP * NJ; i += 256) h[i] = 0ULL;
    __syncthreads();

    const int stride = nb * 256;
    for (int r = blockIdx.x * 256 + threadIdx.x; r < B; r += stride) {
        const float4* p4 = (const float4*)(preds + (size_t)r * NA);
        float4 p0 = p4[0];
        float4 p1 = p4[1];

        float s = __builtin_amdgcn_rcpf(1.0f + __expf(-p0.x))
                + __builtin_amdgcn_rcpf(1.0f + __expf(-p0.y))
                + __builtin_amdgcn_rcpf(1.0f + __expf(-p0.z))
                + __builtin_amdgcn_rcpf(1.0f + __expf(-p0.w))
                + __builtin_amdgcn_rcpf(1.0f + __expf(-p1.x))
                + __builtin_amdgcn_rcpf(1.0f + __expf(-p1.y))
                + __builtin_amdgcn_rcpf(1.0f + __expf(-p1.z))
                + __builtin_amdgcn_rcpf(1.0f + __expf(-p1.w));
        float per_node = s * 0.125f;               // in (0,1)
        unsigned int fixed = (unsigned int)(per_node * FIX_SCALE);
        unsigned long long add = (1ULL << FIX_SHIFT) | (unsigned long long)fixed;

        const int4* a4 = (const int4*)(attrs + (size_t)r * NA);
        int4 a0 = a4[0];
        int4 a1 = a4[1];

        atomicAdd(&h[0 * NJ + ((a0.x << 4) | a0.y)], add);
        atomicAdd(&h[1 * NJ + ((a0.z << 4) | a0.w)], add);
        atomicAdd(&h[2 * NJ + ((a1.x << 4) | a1.y)], add);
        atomicAdd(&h[3 * NJ + ((a1.z << 4) | a1.w)], add);
    }
    __syncthreads();

    for (int i = threadIdx.x; i < NP * NJ; i += 256) {
        partials[(size_t)i * nb + blockIdx.x] = h[i];
    }
}

// ---------------------------------------------------------------------------
// K2: one block per joint entry (1024 blocks). Coalesced read of nb packed
// partials, unpack, reduce -> joint sum (u64 fixed) + count (u32).
// ---------------------------------------------------------------------------
__global__ __launch_bounds__(256) void k2_reduce(
    const unsigned long long* __restrict__ partials, // [NP*NJ, nb]
    unsigned long long* __restrict__ jsum,           // [NP*NJ]
    unsigned int*       __restrict__ jcnt,           // [NP*NJ]
    int nb)
{
    const int e = blockIdx.x;
    unsigned long long sum = 0ULL;
    unsigned int cnt = 0u;
    for (int b = threadIdx.x; b < nb; b += 256) {
        unsigned long long p = partials[(size_t)e * nb + b];
        cnt += (unsigned int)(p >> FIX_SHIFT);
        sum += (p & FIX_MASK);
    }
    for (int off = 32; off > 0; off >>= 1) {
        sum += __shfl_down(sum, off, 64);
        cnt += __shfl_down(cnt, off, 64);
    }
    __shared__ unsigned long long ws_[4];
    __shared__ unsigned int wc_[4];
    const int wave = threadIdx.x >> 6;
    if ((threadIdx.x & 63) == 0) { ws_[wave] = sum; wc_[wave] = cnt; }
    __syncthreads();
    if (threadIdx.x == 0) {
        jsum[e] = ws_[0] + ws_[1] + ws_[2] + ws_[3];
        jcnt[e] = wc_[0] + wc_[1] + wc_[2] + wc_[3];
    }
}

// ---------------------------------------------------------------------------
// K3: 1 block, 128 threads (one per segment). Marginalize joint tables to
// per-segment (sum,count): even attr of pair sums over low nibble, odd attr
// over high nibble. Then fp64 means + pairwise loss + scalar out.
// ---------------------------------------------------------------------------
__global__ __launch_bounds__(128) void k3_finalize(
    const unsigned long long* __restrict__ jsum,
    const unsigned int*       __restrict__ jcnt,
    float* __restrict__ out)
{
    __shared__ double s_mean[NS];
    __shared__ int    s_pres[NS];

    const int t = threadIdx.x;           // segment id
    const int a = t >> 4;                // attribute 0..7
    const int v = t & (NV - 1);          // value 0..15
    const int p = a >> 1;                // pair 0..3

    unsigned long long S = 0ULL;
    unsigned int C = 0u;
    if ((a & 1) == 0) {
        // even attr: its value is the HIGH nibble -> sum over low nibble
        for (int j = 0; j < NV; ++j) {
            const int e = p * NJ + (v << 4) + j;
            S += jsum[e]; C += jcnt[e];
        }
    } else {
        // odd attr: its value is the LOW nibble -> sum over high nibble
        for (int i = 0; i < NV; ++i) {
            const int e = p * NJ + (i << 4) + v;
            S += jsum[e]; C += jcnt[e];
        }
    }
    s_pres[t] = (C > 0u) ? 1 : 0;
    s_mean[t] = (C > 0u)
        ? ((double)S * (1.0 / (double)FIX_SCALE)) / (double)C : 0.0;
    __syncthreads();

    const int i0 = v;
    double loss = 0.0;
    int    ncmp = 0;
    if (s_pres[t]) {
        const double mi = s_mean[t];
        for (int j = i0 + 1; j < NV; ++j) {
            const int sj = (a << 4) + j;
            if (s_pres[sj]) {
                const double d = mi - s_mean[sj];
                loss += d * d;
                ncmp += 1;
            }
        }
    }
    for (int off = 32; off > 0; off >>= 1) {
        loss += __shfl_down(loss, off, 64);
        ncmp += __shfl_down(ncmp, off, 64);
    }
    __shared__ double w_loss[2];
    __shared__ int    w_ncmp[2];
    const int wave = t >> 6;
    if ((t & 63) == 0) { w_loss[wave] = loss; w_ncmp[wave] = ncmp; }
    __syncthreads();
    if (t == 0) {
        const double total = w_loss[0] + w_loss[1];
        const int    n     = w_ncmp[0] + w_ncmp[1];
        out[0] = (n > 0) ? (float)(total / (double)n) : 0.0f;
    }
}

extern "C" void kernel_launch(void* const* d_in, const int* in_sizes, int n_in,
                              void* d_out, int out_size, void* d_ws, size_t ws_size,
                              hipStream_t stream) {
    const float* preds = (const float*)d_in[0];
    const int*   attrs = (const int*)d_in[1];
    float*       out   = (float*)d_out;

    const int B = in_sizes[1] / NA;

    // workspace: partials [NP*NJ, nb] u64  +  jsum [1024] u64  +  jcnt [1024] u32
    const size_t tail = (size_t)NP * NJ * (sizeof(unsigned long long) + sizeof(unsigned int));
    int nb = 2048;                                     // 8 blocks/CU
    while (nb > 256 &&
           (size_t)NP * NJ * nb * sizeof(unsigned long long) + tail > ws_size) {
        nb >>= 1;
    }

    unsigned long long* partials = (unsigned long long*)d_ws;
    unsigned long long* jsum = (unsigned long long*)((char*)d_ws +
        (size_t)NP * NJ * nb * sizeof(unsigned long long));
    unsigned int* jcnt = (unsigned int*)(jsum + NP * NJ);

    k1_accum<<<nb, 256, 0, stream>>>(preds, attrs, partials, B, nb);
    k2_reduce<<<NP * NJ, 256, 0, stream>>>(partials, jsum, jcnt, nb);
    k3_finalize<<<1, 128, 0, stream>>>(jsum, jcnt, out);
}

// Round 4
// 159.485 us; speedup vs baseline: 1.0791x; 1.0791x over previous
//
#include <hip/hip_runtime.h>

#define NA 8
#define NV 16
#define NS (NA * NV)          // 128 segments
#define NP 4                  // attribute pairs
#define NJ 256                // joint entries per pair (16*16)
#define NE (NP * NJ)          // 1024 joint entries total
#define FIX_SHIFT 43
#define FIX_MASK ((1ULL << FIX_SHIFT) - 1)
#define FIX_SCALE 2147483648.0f   // 2^31

// ---------------------------------------------------------------------------
// K1: per-row sigmoid mean -> 4 packed ds_add_u64 into pair-joint histograms
// (256 entries/pair; 64 lanes scatter over 256 addrs -> no same-addr RMW
// serialization; R3 counters confirmed conflicts halved).
// packed = count<<43 | round(per_node * 2^31). nb=1024 -> rows/block <= 1954:
// sum < 2^42, count < 2^11 -> no field overflow.
// Epilogue layout FIX (the R3 regression): partials[block][entry] so thread t
// stores entries {t, t+256, t+512, t+768} -> fully coalesced, 8 MB total,
// instead of 2M scattered cachelines (76 MB WRITE_SIZE in R3).
// ---------------------------------------------------------------------------
__global__ __launch_bounds__(256) void k1_accum(
    const float* __restrict__ preds,           // [B, 8]
    const int*   __restrict__ attrs,           // [B, 8]
    unsigned long long* __restrict__ partials, // [nb, NE]
    int B, int nb)
{
    __shared__ unsigned long long h[NE];   // 8 KB
    for (int i = threadIdx.x; i < NE; i += 256) h[i] = 0ULL;
    __syncthreads();

    const int stride = nb * 256;
    for (int r = blockIdx.x * 256 + threadIdx.x; r < B; r += stride) {
        const float4* p4 = (const float4*)(preds + (size_t)r * NA);
        float4 p0 = p4[0];
        float4 p1 = p4[1];

        float s = __builtin_amdgcn_rcpf(1.0f + __expf(-p0.x))
                + __builtin_amdgcn_rcpf(1.0f + __expf(-p0.y))
                + __builtin_amdgcn_rcpf(1.0f + __expf(-p0.z))
                + __builtin_amdgcn_rcpf(1.0f + __expf(-p0.w))
                + __builtin_amdgcn_rcpf(1.0f + __expf(-p1.x))
                + __builtin_amdgcn_rcpf(1.0f + __expf(-p1.y))
                + __builtin_amdgcn_rcpf(1.0f + __expf(-p1.z))
                + __builtin_amdgcn_rcpf(1.0f + __expf(-p1.w));
        float per_node = s * 0.125f;               // in (0,1)
        unsigned int fixed = (unsigned int)(per_node * FIX_SCALE);
        unsigned long long add = (1ULL << FIX_SHIFT) | (unsigned long long)fixed;

        const int4* a4 = (const int4*)(attrs + (size_t)r * NA);
        int4 a0 = a4[0];
        int4 a1 = a4[1];

        atomicAdd(&h[0 * NJ + ((a0.x << 4) | a0.y)], add);
        atomicAdd(&h[1 * NJ + ((a0.z << 4) | a0.w)], add);
        atomicAdd(&h[2 * NJ + ((a1.x << 4) | a1.y)], add);
        atomicAdd(&h[3 * NJ + ((a1.z << 4) | a1.w)], add);
    }
    __syncthreads();

    unsigned long long* dst = partials + (size_t)blockIdx.x * NE;
    for (int i = threadIdx.x; i < NE; i += 256) {
        dst[i] = h[i];     // coalesced: consecutive threads -> consecutive u64
    }
}

// ---------------------------------------------------------------------------
// K2: one block per joint entry (1024 blocks). Lanes stride 8 KB across the
// [block][entry] table — uncoalesced, but the 8 MB table is L2/L3-resident
// (just written), so the 8x line amplification costs ~2-4 us, paid here
// instead of in k1's write path.
// ---------------------------------------------------------------------------
__global__ __launch_bounds__(256) void k2_reduce(
    const unsigned long long* __restrict__ partials, // [nb, NE]
    unsigned long long* __restrict__ jsum,           // [NE]
    unsigned int*       __restrict__ jcnt,           // [NE]
    int nb)
{
    const int e = blockIdx.x;
    unsigned long long sum = 0ULL;
    unsigned int cnt = 0u;
    for (int b = threadIdx.x; b < nb; b += 256) {
        unsigned long long p = partials[(size_t)b * NE + e];
        cnt += (unsigned int)(p >> FIX_SHIFT);
        sum += (p & FIX_MASK);
    }
    for (int off = 32; off > 0; off >>= 1) {
        sum += __shfl_down(sum, off, 64);
        cnt += __shfl_down(cnt, off, 64);
    }
    __shared__ unsigned long long ws_[4];
    __shared__ unsigned int wc_[4];
    const int wave = threadIdx.x >> 6;
    if ((threadIdx.x & 63) == 0) { ws_[wave] = sum; wc_[wave] = cnt; }
    __syncthreads();
    if (threadIdx.x == 0) {
        jsum[e] = ws_[0] + ws_[1] + ws_[2] + ws_[3];
        jcnt[e] = wc_[0] + wc_[1] + wc_[2] + wc_[3];
    }
}

// ---------------------------------------------------------------------------
// K3: 1 block, 128 threads (one per segment). Marginalize joint tables to
// per-segment (sum,count), fp64 means + pairwise loss, scalar out.
// ---------------------------------------------------------------------------
__global__ __launch_bounds__(128) void k3_finalize(
    const unsigned long long* __restrict__ jsum,
    const unsigned int*       __restrict__ jcnt,
    float* __restrict__ out)
{
    __shared__ double s_mean[NS];
    __shared__ int    s_pres[NS];

    const int t = threadIdx.x;           // segment id
    const int a = t >> 4;                // attribute 0..7
    const int v = t & (NV - 1);          // value 0..15
    const int p = a >> 1;                // pair 0..3

    unsigned long long S = 0ULL;
    unsigned int C = 0u;
    if ((a & 1) == 0) {
        for (int j = 0; j < NV; ++j) {   // even attr = high nibble
            const int e = p * NJ + (v << 4) + j;
            S += jsum[e]; C += jcnt[e];
        }
    } else {
        for (int i = 0; i < NV; ++i) {   // odd attr = low nibble
            const int e = p * NJ + (i << 4) + v;
            S += jsum[e]; C += jcnt[e];
        }
    }
    s_pres[t] = (C > 0u) ? 1 : 0;
    s_mean[t] = (C > 0u)
        ? ((double)S * (1.0 / (double)FIX_SCALE)) / (double)C : 0.0;
    __syncthreads();

    double loss = 0.0;
    int    ncmp = 0;
    if (s_pres[t]) {
        const double mi = s_mean[t];
        for (int j = v + 1; j < NV; ++j) {
            const int sj = (a << 4) + j;
            if (s_pres[sj]) {
                const double d = mi - s_mean[sj];
                loss += d * d;
                ncmp += 1;
            }
        }
    }
    for (int off = 32; off > 0; off >>= 1) {
        loss += __shfl_down(loss, off, 64);
        ncmp += __shfl_down(ncmp, off, 64);
    }
    __shared__ double w_loss[2];
    __shared__ int    w_ncmp[2];
    const int wave = t >> 6;
    if ((t & 63) == 0) { w_loss[wave] = loss; w_ncmp[wave] = ncmp; }
    __syncthreads();
    if (t == 0) {
        const double total = w_loss[0] + w_loss[1];
        const int    n     = w_ncmp[0] + w_ncmp[1];
        out[0] = (n > 0) ? (float)(total / (double)n) : 0.0f;
    }
}

extern "C" void kernel_launch(void* const* d_in, const int* in_sizes, int n_in,
                              void* d_out, int out_size, void* d_ws, size_t ws_size,
                              hipStream_t stream) {
    const float* preds = (const float*)d_in[0];
    const int*   attrs = (const int*)d_in[1];
    float*       out   = (float*)d_out;

    const int B = in_sizes[1] / NA;

    // workspace: partials [nb, NE] u64 + jsum [NE] u64 + jcnt [NE] u32
    const size_t tail = (size_t)NE * (sizeof(unsigned long long) + sizeof(unsigned int));
    int nb = 1024;                                     // 4 blocks/CU
    while (nb > 256 &&
           (size_t)NE * nb * sizeof(unsigned long long) + tail > ws_size) {
        nb >>= 1;
    }

    unsigned long long* partials = (unsigned long long*)d_ws;
    unsigned long long* jsum = (unsigned long long*)((char*)d_ws +
        (size_t)NE * nb * sizeof(unsigned long long));
    unsigned int* jcnt = (unsigned int*)(jsum + NE);

    k1_accum<<<nb, 256, 0, stream>>>(preds, attrs, partials, B, nb);
    k2_reduce<<<NE, 256, 0, stream>>>(partials, jsum, jcnt, nb);
    k3_finalize<<<1, 128, 0, stream>>>(jsum, jcnt, out);
}